// Round 19
// baseline (196.317 us; speedup 1.0000x reference)
//
#include <hip/hip_runtime.h>
#include <hip/hip_bf16.h>
#include <hip/hip_fp16.h>
#include <stdint.h>

typedef __attribute__((ext_vector_type(8))) _Float16 f16x8;
typedef __attribute__((ext_vector_type(4))) float f32x4;

#define B_  32
#define S_  512
#define K_  512
#define H_  1024
#define HS  64           // h-cols per block
#define SC  128          // s-rows per chunk
#define NKT 8            // K_/64
#define NSC 4            // S_/SC

// LDS: x dbuf 2x16K | W dbuf 2x24K = 80KB -> 2 blocks/CU.
// handoff (2 sw x 64 h x {F,G} f32 = 1KB) aliases WD1 rows 184..191 (r11-
// proven hazard window: written during epilogue after the post-activation
// barrier; re-staged by the next sc's kt0 STAGEH, which issues after
// GATE(kt0) -- by then backfill has consumed HOF).
#define XD0 0
#define XD1 16384
#define WD0 32768
#define WD1 57344
#define HOF (WD1 + 24576 - 1024)
#define LDS_BYTES 81920

#define GLDS(src, dst) __builtin_amdgcn_global_load_lds( \
    (const __attribute__((address_space(1))) void*)(src), \
    (__attribute__((address_space(3))) void*)(dst), 16, 0, 0)

__device__ inline float sigm(float v) {
    return __builtin_amdgcn_rcpf(1.f + __expf(-v));
}

// ---------------------------------------------------------------------------
// f32 -> f16 conversion for x and W. 8 elems/thread, 16B stores.
// ---------------------------------------------------------------------------
struct alignas(16) H8 { _Float16 h[8]; };

__global__ __launch_bounds__(256) void cvt_xw(
    const float* __restrict__ x, _Float16* __restrict__ xh, int n8x,
    const float* __restrict__ W, _Float16* __restrict__ Wh, int n8w)
{
    const int t = blockIdx.x * 256 + threadIdx.x;
    const float* src; _Float16* dst; int i;
    if (t < n8x)             { src = x; dst = xh; i = t; }
    else if (t < n8x + n8w)  { src = W; dst = Wh; i = t - n8x; }
    else return;
    const float4* p = (const float4*)(src + (size_t)i * 8);
    const float4 a = p[0], b = p[1];
    H8 o;
    o.h[0] = (_Float16)a.x; o.h[1] = (_Float16)a.y;
    o.h[2] = (_Float16)a.z; o.h[3] = (_Float16)a.w;
    o.h[4] = (_Float16)b.x; o.h[5] = (_Float16)b.y;
    o.h[6] = (_Float16)b.z; o.h[7] = (_Float16)b.w;
    ((H8*)dst)[i] = o;
}

// ---------------------------------------------------------------------------
// Fused GEMM + activations + in-register affine scan (r18 structure).
// r19 changes:
//  (1) Fine-grained counted lgkm within each ks: frag reads order-pinned
//      (volatile ds loads: af0..3 then bf0..5; DS retires in order, no SMEM
//      in-loop) -> lgkm(4){MFMA n0,n1} lgkm(2){n2,n3} lgkm(0){n4,n5}.
//      MFMAs start after 6 of 10 reads land; zero extra registers (all 10
//      frags live through the block anyway).
//  (2) Post-K barrier moved BELOW the activation/compose block: each wave's
//      own lgkm(0) already retired its kt7 reads, so the barrier is only
//      needed before the HOF write (WD1 alias). Fast waves' epilogue VALU
//      overlaps slow waves' K-tail.
// ---------------------------------------------------------------------------
__global__ __launch_bounds__(256, 2) void qrnn_fused(
    const _Float16* __restrict__ xh,   // [B*S, K]  (Wh = xh + B*S*K)
    const _Float16* __restrict__ Wh,   // [3H, K]
    const float* __restrict__ bias,    // [3H]
    const float* __restrict__ c0,      // [B, H]
    float* __restrict__ out)           // [B,S,H] ++ [B,H]
{
    extern __shared__ char smem[];

    const int tid  = threadIdx.x;
    const int lane = tid & 63;
    const int wid  = tid >> 6;
    const int gw   = wid & 1;          // h-half (32 h)
    const int sw   = wid >> 1;         // s-half (64 s)
    const int fq   = lane >> 4;
    const int fr   = lane & 15;

    const int bid = blockIdx.x;
    const int b   = (bid & 7) + ((bid >> 7) << 3);
    const int hs  = (bid >> 3) & 15;

    // per-lane h columns (nn = 0,1) and bias
    float bz[2], bff[2], bo[2], cc[2];
    #pragma unroll
    for (int nn = 0; nn < 2; ++nn) {
        const int hcol = hs * HS + gw * 32 + nn * 16 + fr;
        bz[nn]  = bias[hcol];
        bff[nn] = bias[H_ + hcol];
        bo[nn]  = bias[2 * H_ + hcol];
        cc[nn]  = c0[b * H_ + hcol];
    }

    const int srow  = lane >> 3;
    const int scolb = (((lane & 7) ^ (lane >> 3)) << 4);

    // ---- precomputed staging offsets (32-bit, absolute from xh) ------------
    uint32_t voff[10];
    int ldstA[10], ldstB[10];
    #pragma unroll
    for (int i = 0; i < 10; ++i) {
        const int cid = wid * 10 + i;
        if (cid < 16) {                // x chunk
            const int r = cid * 8 + srow;
            voff[i]  = (uint32_t)((b * S_ + r) * (K_ * 2)) + (uint32_t)scolb;
            ldstA[i] = XD0 + cid * 1024;
            ldstB[i] = XD1 + cid * 1024;
        } else {                       // W chunk (Wh = xh + 32MB)
            const int r = (cid - 16) * 8 + srow;
            const int wrow = (r >> 6) * H_ + hs * HS + (r & 63);
            voff[i]  = (uint32_t)(B_ * S_ * K_ * 2) + (uint32_t)(wrow * (K_ * 2)) + (uint32_t)scolb;
            ldstA[i] = WD0 + (cid - 16) * 1024;
            ldstB[i] = WD1 + (cid - 16) * 1024;
        }
    }

    // half-stage: ks=0 issues i=0..4, ks=1 issues i=5..9
    auto STAGEH = [&](int ktimm, bool pB, int half) {
        #pragma unroll
        for (int i = half * 5; i < half * 5 + 5; ++i) {
            GLDS((const char*)xh + ktimm * 128 + (size_t)voff[i],
                 smem + (pB ? ldstB[i] : ldstA[i]));
        }
    };

    // ---- precomputed frag read offsets (swizzle + ks baked in) -------------
    int afoK[2][4], bfoK[2][6];
    #pragma unroll
    for (int ks = 0; ks < 2; ++ks) {
        #pragma unroll
        for (int m = 0; m < 4; ++m) {
            const int row = sw * 64 + m * 16 + fr;
            const int kb  = ks * 64 + fq * 16;
            afoK[ks][m] = row * 128 + (kb ^ ((row & 7) << 4));
        }
        #pragma unroll
        for (int n = 0; n < 6; ++n) {
            const int row = (n >> 1) * 64 + gw * 32 + (n & 1) * 16 + fr;
            const int kb  = ks * 64 + fq * 16;
            bfoK[ks][n] = row * 128 + (kb ^ ((row & 7) << 4));
        }
    }

    STAGEH(0, false, 0);
    STAGEH(0, false, 1);
    asm volatile("s_waitcnt vmcnt(0)" ::: "memory");   // drain prologue stage

    for (int sc = 0; sc < NSC; ++sc) {
        f32x4 acc[4][6] = {};

        #pragma unroll
        for (int kt = 0; kt < NKT; ++kt) {
            const int cur  = kt & 1;
            const int curx = cur ? XD1 : XD0;
            const int curw = cur ? WD1 : WD0;
            const bool nxtB = !cur;    // stage target parity

            // --- GATE: cur buffer landed on all waves ----------------------
            if (kt == 0) {
                // 32 backfill stores (newer) may fly; 10 stage loads (older,
                // FIFO) forced complete. (sc==0: nothing outstanding.)
                asm volatile("s_waitcnt vmcnt(32)" ::: "memory");
            } else {
                asm volatile("s_waitcnt vmcnt(0)" ::: "memory");
            }
            __builtin_amdgcn_s_barrier();
            __builtin_amdgcn_sched_barrier(0);

            // bump x staging offsets to next chunk before kt7's prestage
            if (kt == NKT - 1 && sc + 1 < NSC) {
                #pragma unroll
                for (int i = 0; i < 10; ++i)
                    if (wid * 10 + i < 16) voff[i] += SC * K_ * 2;
            }

            #pragma unroll
            for (int ks = 0; ks < 2; ++ks) {
                // order-pinned reads: af0..3 then bf0..5 (volatile)
                f16x8 af[4], bf[6];
                #pragma unroll
                for (int m = 0; m < 4; ++m)
                    af[m] = *(volatile const f16x8*)(smem + curx + afoK[ks][m]);
                #pragma unroll
                for (int n = 0; n < 6; ++n)
                    bf[n] = *(volatile const f16x8*)(smem + curw + bfoK[ks][n]);

                // half-stage for kt+1 under this sub-phase (vmcnt only)
                if (kt + 1 < NKT)      STAGEH(kt + 1, nxtB, ks);
                else if (sc + 1 < NSC) STAGEH(0, nxtB, ks);

                __builtin_amdgcn_s_setprio(1);
                asm volatile("s_waitcnt lgkmcnt(4)" ::: "memory");
                __builtin_amdgcn_sched_barrier(0);
                #pragma unroll
                for (int n = 0; n < 2; ++n)
                    #pragma unroll
                    for (int m = 0; m < 4; ++m)
                        acc[m][n] = __builtin_amdgcn_mfma_f32_16x16x32_f16(
                            af[m], bf[n], acc[m][n], 0, 0, 0);
                asm volatile("s_waitcnt lgkmcnt(2)" ::: "memory");
                __builtin_amdgcn_sched_barrier(0);
                #pragma unroll
                for (int n = 2; n < 4; ++n)
                    #pragma unroll
                    for (int m = 0; m < 4; ++m)
                        acc[m][n] = __builtin_amdgcn_mfma_f32_16x16x32_f16(
                            af[m], bf[n], acc[m][n], 0, 0, 0);
                asm volatile("s_waitcnt lgkmcnt(0)" ::: "memory");
                __builtin_amdgcn_sched_barrier(0);
                #pragma unroll
                for (int n = 4; n < 6; ++n)
                    #pragma unroll
                    for (int m = 0; m < 4; ++m)
                        acc[m][n] = __builtin_amdgcn_mfma_f32_16x16x32_f16(
                            af[m], bf[n], acc[m][n], 0, 0, 0);
                __builtin_amdgcn_s_setprio(0);
                // no intra-kt barriers: ks1 reads issue under MFMA ks0 drain
            }
        }

        // ---- activations + per-lane affine composition (register-only) ------
        // Runs BEFORE the barrier: wave-local, no LDS-storage access
        // (shuffles use the DS pipe but not WD1 storage).
        float FsS[2][4], GsS[2][4];
        float FP[2], GP[2];
        #pragma unroll
        for (int nn = 0; nn < 2; ++nn) {
            FP[nn] = 1.f; GP[nn] = 0.f;
            #pragma unroll
            for (int m = 0; m < 4; ++m) {
                float Fr = 1.f, Gr = 0.f;
                #pragma unroll
                for (int j = 0; j < 4; ++j) {
                    const float z = 2.f * sigm(2.f * (acc[m][nn][j] + bz[nn])) - 1.f;
                    const float f = sigm(acc[m][2 + nn][j] + bff[nn]);
                    const float g = (1.f - f) * z;
                    acc[m][nn][j]     = g;
                    acc[m][2 + nn][j] = f;
                    acc[m][4 + nn][j] = sigm(acc[m][4 + nn][j] + bo[nn]);
                    Gr = __builtin_fmaf(f, Gr, g);
                    Fr = f * Fr;
                }
                // Kogge-Stone over fq (4 groups of 16 lanes)
                float F1 = __shfl(Fr, lane - 16), G1 = __shfl(Gr, lane - 16);
                if (fq >= 1) { Gr = __builtin_fmaf(Fr, G1, Gr); Fr = Fr * F1; }
                float F2 = __shfl(Fr, lane - 32), G2 = __shfl(Gr, lane - 32);
                if (fq >= 2) { Gr = __builtin_fmaf(Fr, G2, Gr); Fr = Fr * F2; }
                float FE = __shfl(Fr, lane - 16), GE = __shfl(Gr, lane - 16);
                if (fq == 0) { FE = 1.f; GE = 0.f; }
                const float FM = __shfl(Fr, 48 + fr);
                const float GM = __shfl(Gr, 48 + fr);
                FsS[nn][m] = FE * FP[nn];
                GsS[nn][m] = __builtin_fmaf(FE, GP[nn], GE);
                GP[nn] = __builtin_fmaf(FM, GP[nn], GM);
                FP[nn] = FM * FP[nn];
            }
        }

        // all waves past their kt7 lgkm(0) (reads retired) before HOF write
        __builtin_amdgcn_s_barrier();

        // ---- handoff: per-h wave-total (F,G) between sw waves ---------------
        if (fq == 0) {
            #pragma unroll
            for (int nn = 0; nn < 2; ++nn) {
                const int hh = gw * 32 + nn * 16 + fr;
                *(float2*)(smem + HOF + sw * 512 + hh * 8) = make_float2(FP[nn], GP[nn]);
            }
        }
        asm volatile("s_waitcnt lgkmcnt(0)" ::: "memory");
        __builtin_amdgcn_s_barrier();

        // ---- backfill + out stores ------------------------------------------
        #pragma unroll
        for (int nn = 0; nn < 2; ++nn) {
            const int hh = gw * 32 + nn * 16 + fr;
            const float2 m0 = *(const float2*)(smem + HOF + hh * 8);
            const float2 m1 = *(const float2*)(smem + HOF + 512 + hh * 8);
            const float cin = (sw == 0) ? cc[nn]
                                        : __builtin_fmaf(m0.x, cc[nn], m0.y);
            #pragma unroll
            for (int m = 0; m < 4; ++m) {
                float cr = __builtin_fmaf(FsS[nn][m], cin, GsS[nn][m]);
                #pragma unroll
                for (int j = 0; j < 4; ++j) {
                    cr = __builtin_fmaf(acc[m][2 + nn][j], cr, acc[m][nn][j]);
                    const int sg = b * S_ + sc * SC + sw * 64 + m * 16 + fq * 4 + j;
                    out[(size_t)sg * H_ + hs * HS + hh] = acc[m][4 + nn][j] * cr;
                }
            }
            cc[nn] = __builtin_fmaf(m1.x, __builtin_fmaf(m0.x, cc[nn], m0.y), m1.y);
        }
        // HOF reads completed before their dependent stores issued; next GATE
        // barrier precedes any WD1/HOF overwrite (stage issues after GATE).
    }

    // c_last tail: [1,B,H] appended after [B,S,H]
    if (sw == 0 && fq == 0) {
        #pragma unroll
        for (int nn = 0; nn < 2; ++nn)
            out[(size_t)B_ * S_ * H_ + b * H_ + hs * HS + gw * 32 + nn * 16 + fr] = cc[nn];
    }
}

extern "C" void kernel_launch(void* const* d_in, const int* in_sizes, int n_in,
                              void* d_out, int out_size, void* d_ws, size_t ws_size,
                              hipStream_t stream) {
    const float* x = (const float*)d_in[0];
    const float* h = (const float*)d_in[1];
    const float* W = (const float*)d_in[2];
    const float* b = (const float*)d_in[3];
    float* out = (float*)d_out;

    _Float16* xh = (_Float16*)d_ws;
    _Float16* Wh = xh + (size_t)B_ * S_ * K_;   // contiguous: Wh - xh = 32MB

    (void)hipFuncSetAttribute((const void*)qrnn_fused,
                              hipFuncAttributeMaxDynamicSharedMemorySize, LDS_BYTES);

    const int n8x = B_ * S_ * K_ / 8;   // 1048576
    const int n8w = 3 * H_ * K_ / 8;    // 196608
    cvt_xw<<<(n8x + n8w + 255) / 256, 256, 0, stream>>>(x, xh, n8x, W, Wh, n8w);

    qrnn_fused<<<B_ * (H_ / HS), 256, LDS_BYTES, stream>>>(xh, Wh, b, h, out);
}

// Round 20
// 69.303 us; speedup vs baseline: 2.8327x; 2.8327x over previous
//
#include <hip/hip_runtime.h>
#include <hip/hip_bf16.h>
#include <hip/hip_fp16.h>
#include <stdint.h>

typedef __attribute__((ext_vector_type(8))) _Float16 f16x8;
typedef __attribute__((ext_vector_type(4))) float f32x4;

#define B_  32
#define S_  512
#define K_  512
#define H_  1024
#define HS  64           // h-cols per block
#define SC  128          // s-rows per chunk
#define NKT 8            // K_/64
#define NSC 4            // S_/SC

// LDS: x dbuf 2x16K | W dbuf 2x24K = 80KB -> 2 blocks/CU.
// handoff (2 sw x 64 h x {F,G} f32 = 1KB) aliases WD1 rows 184..191 (r11-
// proven hazard window).
// r20: x rows enter LDS PERMUTED: LDS row r holds global s-row sigma(r),
// sigma = bit-swap [5:4]<->[3:2] within each 64-row half. Read path is
// byte-identical to r18 (0 conflicts); output C-row of tile m, lane(fq,j)
// becomes s = fq*16 + m*4 + j -> each lane owns 16 CONTIGUOUS s-steps ->
// scan needs ONE Kogge-Stone per nn (16 shuffles/chunk vs 64).
#define XD0 0
#define XD1 16384
#define WD0 32768
#define WD1 57344
#define HOF (WD1 + 24576 - 1024)
#define LDS_BYTES 81920

#define GLDS(src, dst) __builtin_amdgcn_global_load_lds( \
    (const __attribute__((address_space(1))) void*)(src), \
    (__attribute__((address_space(3))) void*)(dst), 16, 0, 0)

__device__ inline float sigm(float v) {
    return __builtin_amdgcn_rcpf(1.f + __expf(-v));
}

// ---------------------------------------------------------------------------
// f32 -> f16 conversion for x and W. 8 elems/thread, 16B stores.
// ---------------------------------------------------------------------------
struct alignas(16) H8 { _Float16 h[8]; };

__global__ __launch_bounds__(256) void cvt_xw(
    const float* __restrict__ x, _Float16* __restrict__ xh, int n8x,
    const float* __restrict__ W, _Float16* __restrict__ Wh, int n8w)
{
    const int t = blockIdx.x * 256 + threadIdx.x;
    const float* src; _Float16* dst; int i;
    if (t < n8x)             { src = x; dst = xh; i = t; }
    else if (t < n8x + n8w)  { src = W; dst = Wh; i = t - n8x; }
    else return;
    const float4* p = (const float4*)(src + (size_t)i * 8);
    const float4 a = p[0], b = p[1];
    H8 o;
    o.h[0] = (_Float16)a.x; o.h[1] = (_Float16)a.y;
    o.h[2] = (_Float16)a.z; o.h[3] = (_Float16)a.w;
    o.h[4] = (_Float16)b.x; o.h[5] = (_Float16)b.y;
    o.h[6] = (_Float16)b.z; o.h[7] = (_Float16)b.w;
    ((H8*)dst)[i] = o;
}

// ---------------------------------------------------------------------------
// Fused GEMM + activations + in-register affine scan (r18 structure).
// r20 change: sigma-permuted x rows (via voff precompute only) ->
// lane-contiguous 16-step scan runs -> single Kogge-Stone per nn.
// K-loop, GATE/vmcnt discipline, barriers: byte-identical to r18.
// ---------------------------------------------------------------------------
__global__ __launch_bounds__(256, 2) void qrnn_fused(
    const _Float16* __restrict__ xh,   // [B*S, K]  (Wh = xh + B*S*K)
    const _Float16* __restrict__ Wh,   // [3H, K]
    const float* __restrict__ bias,    // [3H]
    const float* __restrict__ c0,      // [B, H]
    float* __restrict__ out)           // [B,S,H] ++ [B,H]
{
    extern __shared__ char smem[];

    const int tid  = threadIdx.x;
    const int lane = tid & 63;
    const int wid  = tid >> 6;
    const int gw   = wid & 1;          // h-half (32 h)
    const int sw   = wid >> 1;         // s-half (64 s)
    const int fq   = lane >> 4;
    const int fr   = lane & 15;

    const int bid = blockIdx.x;
    const int b   = (bid & 7) + ((bid >> 7) << 3);
    const int hs  = (bid >> 3) & 15;

    // per-lane h columns (nn = 0,1) and bias
    float bz[2], bff[2], bo[2], cc[2];
    #pragma unroll
    for (int nn = 0; nn < 2; ++nn) {
        const int hcol = hs * HS + gw * 32 + nn * 16 + fr;
        bz[nn]  = bias[hcol];
        bff[nn] = bias[H_ + hcol];
        bo[nn]  = bias[2 * H_ + hcol];
        cc[nn]  = c0[b * H_ + hcol];
    }

    const int srow  = lane >> 3;
    const int scolb = (((lane & 7) ^ (lane >> 3)) << 4);

    // ---- precomputed staging offsets (32-bit, absolute from xh) ------------
    // x rows are sigma-permuted: LDS row r <- global s-row sigma(r),
    // sigma(r) = (r&64) | ((r>>2)&3)<<4 | ((r>>4)&3)<<2 | (r&3).
    uint32_t voff[10];
    int ldstA[10], ldstB[10];
    #pragma unroll
    for (int i = 0; i < 10; ++i) {
        const int cid = wid * 10 + i;
        if (cid < 16) {                // x chunk (permuted rows)
            const int r  = cid * 8 + srow;
            const int rl = r & 63;
            const int sg = (r & 64) + (((rl >> 2) & 3) << 4)
                         + (((rl >> 4) & 3) << 2) + (rl & 3);
            voff[i]  = (uint32_t)((b * S_ + sg) * (K_ * 2)) + (uint32_t)scolb;
            ldstA[i] = XD0 + cid * 1024;
            ldstB[i] = XD1 + cid * 1024;
        } else {                       // W chunk (Wh = xh + 32MB)
            const int r = (cid - 16) * 8 + srow;
            const int wrow = (r >> 6) * H_ + hs * HS + (r & 63);
            voff[i]  = (uint32_t)(B_ * S_ * K_ * 2) + (uint32_t)(wrow * (K_ * 2)) + (uint32_t)scolb;
            ldstA[i] = WD0 + (cid - 16) * 1024;
            ldstB[i] = WD1 + (cid - 16) * 1024;
        }
    }

    // half-stage: ks=0 issues i=0..4, ks=1 issues i=5..9
    auto STAGEH = [&](int ktimm, bool pB, int half) {
        #pragma unroll
        for (int i = half * 5; i < half * 5 + 5; ++i) {
            GLDS((const char*)xh + ktimm * 128 + (size_t)voff[i],
                 smem + (pB ? ldstB[i] : ldstA[i]));
        }
    };

    // ---- precomputed frag read offsets (identical to r18) ------------------
    int afoK[2][4], bfoK[2][6];
    #pragma unroll
    for (int ks = 0; ks < 2; ++ks) {
        #pragma unroll
        for (int m = 0; m < 4; ++m) {
            const int row = sw * 64 + m * 16 + fr;
            const int kb  = ks * 64 + fq * 16;
            afoK[ks][m] = row * 128 + (kb ^ ((row & 7) << 4));
        }
        #pragma unroll
        for (int n = 0; n < 6; ++n) {
            const int row = (n >> 1) * 64 + gw * 32 + (n & 1) * 16 + fr;
            const int kb  = ks * 64 + fq * 16;
            bfoK[ks][n] = row * 128 + (kb ^ ((row & 7) << 4));
        }
    }

    STAGEH(0, false, 0);
    STAGEH(0, false, 1);
    asm volatile("s_waitcnt vmcnt(0)" ::: "memory");   // drain prologue stage

    for (int sc = 0; sc < NSC; ++sc) {
        f32x4 acc[4][6] = {};

        #pragma unroll
        for (int kt = 0; kt < NKT; ++kt) {
            const int cur  = kt & 1;
            const int curx = cur ? XD1 : XD0;
            const int curw = cur ? WD1 : WD0;
            const bool nxtB = !cur;    // stage target parity

            // --- GATE: cur buffer landed on all waves ----------------------
            if (kt == 0) {
                asm volatile("s_waitcnt vmcnt(32)" ::: "memory");
            } else {
                asm volatile("s_waitcnt vmcnt(0)" ::: "memory");
            }
            __builtin_amdgcn_s_barrier();
            __builtin_amdgcn_sched_barrier(0);

            // bump x staging offsets to next chunk before kt7's prestage
            if (kt == NKT - 1 && sc + 1 < NSC) {
                #pragma unroll
                for (int i = 0; i < 10; ++i)
                    if (wid * 10 + i < 16) voff[i] += SC * K_ * 2;
            }

            #pragma unroll
            for (int ks = 0; ks < 2; ++ks) {
                f16x8 af[4], bf[6];
                #pragma unroll
                for (int m = 0; m < 4; ++m)
                    af[m] = *(const f16x8*)(smem + curx + afoK[ks][m]);
                #pragma unroll
                for (int n = 0; n < 6; ++n)
                    bf[n] = *(const f16x8*)(smem + curw + bfoK[ks][n]);

                // half-stage for kt+1 under this sub-phase
                if (kt + 1 < NKT)      STAGEH(kt + 1, nxtB, ks);
                else if (sc + 1 < NSC) STAGEH(0, nxtB, ks);

                asm volatile("s_waitcnt lgkmcnt(0)" ::: "memory");
                __builtin_amdgcn_sched_barrier(0);
                __builtin_amdgcn_s_setprio(1);
                #pragma unroll
                for (int m = 0; m < 4; ++m)
                    #pragma unroll
                    for (int n = 0; n < 6; ++n)
                        acc[m][n] = __builtin_amdgcn_mfma_f32_16x16x32_f16(
                            af[m], bf[n], acc[m][n], 0, 0, 0);
                __builtin_amdgcn_s_setprio(0);
                // no intra-kt barriers (r18)
            }
        }

        // all waves done with kt7 LDS reads (own lgkm(0) + this barrier)
        __builtin_amdgcn_s_barrier();

        // ---- activations + contiguous 16-step composition per lane ----------
        // Lane (fq) owns s-steps sw*64 + fq*16 + (m*4+j), m outer, j inner
        // (s-ascending). acc slots: [m][nn]=g, [m][2+nn]=f, [m][4+nn]=o.
        float FE_[2], GE_[2], FP[2], GP[2];
        #pragma unroll
        for (int nn = 0; nn < 2; ++nn) {
            float Fr = 1.f, Gr = 0.f;
            #pragma unroll
            for (int m = 0; m < 4; ++m) {
                #pragma unroll
                for (int j = 0; j < 4; ++j) {
                    const float z = 2.f * sigm(2.f * (acc[m][nn][j] + bz[nn])) - 1.f;
                    const float f = sigm(acc[m][2 + nn][j] + bff[nn]);
                    const float g = (1.f - f) * z;
                    acc[m][nn][j]     = g;
                    acc[m][2 + nn][j] = f;
                    acc[m][4 + nn][j] = sigm(acc[m][4 + nn][j] + bo[nn]);
                    Gr = __builtin_fmaf(f, Gr, g);
                    Fr = f * Fr;
                }
            }
            // single Kogge-Stone over fq (4 groups of 16 lanes)
            float F1 = __shfl(Fr, lane - 16), G1 = __shfl(Gr, lane - 16);
            if (fq >= 1) { Gr = __builtin_fmaf(Fr, G1, Gr); Fr = Fr * F1; }
            float F2 = __shfl(Fr, lane - 32), G2 = __shfl(Gr, lane - 32);
            if (fq >= 2) { Gr = __builtin_fmaf(Fr, G2, Gr); Fr = Fr * F2; }
            float FE = __shfl(Fr, lane - 16), GE = __shfl(Gr, lane - 16);
            if (fq == 0) { FE = 1.f; GE = 0.f; }
            FE_[nn] = FE;                       // exclusive prefix (run start)
            GE_[nn] = GE;
            FP[nn]  = __shfl(Fr, 48 + fr);      // wave-total map
            GP[nn]  = __shfl(Gr, 48 + fr);
        }

        // ---- handoff: per-h wave-total (F,G) between sw waves ---------------
        if (fq == 0) {
            #pragma unroll
            for (int nn = 0; nn < 2; ++nn) {
                const int hh = gw * 32 + nn * 16 + fr;
                *(float2*)(smem + HOF + sw * 512 + hh * 8) = make_float2(FP[nn], GP[nn]);
            }
        }
        asm volatile("s_waitcnt lgkmcnt(0)" ::: "memory");
        __builtin_amdgcn_s_barrier();

        // ---- backfill + out stores ------------------------------------------
        #pragma unroll
        for (int nn = 0; nn < 2; ++nn) {
            const int hh = gw * 32 + nn * 16 + fr;
            const float2 m0 = *(const float2*)(smem + HOF + hh * 8);
            const float2 m1 = *(const float2*)(smem + HOF + 512 + hh * 8);
            const float cin = (sw == 0) ? cc[nn]
                                        : __builtin_fmaf(m0.x, cc[nn], m0.y);
            float cr = __builtin_fmaf(FE_[nn], cin, GE_[nn]);   // lane run start
            float* orow = out + (size_t)(b * S_ + sc * SC + sw * 64 + fq * 16) * H_
                        + hs * HS + hh;
            #pragma unroll
            for (int m = 0; m < 4; ++m) {
                #pragma unroll
                for (int j = 0; j < 4; ++j) {
                    cr = __builtin_fmaf(acc[m][2 + nn][j], cr, acc[m][nn][j]);
                    orow[(size_t)(m * 4 + j) * H_] = acc[m][4 + nn][j] * cr;
                }
            }
            cc[nn] = __builtin_fmaf(m1.x, __builtin_fmaf(m0.x, cc[nn], m0.y), m1.y);
        }
        // HOF reads completed before their dependent stores issued; next GATE
        // barrier precedes any WD1/HOF overwrite (stage issues after GATE).
    }

    // c_last tail: [1,B,H] appended after [B,S,H]
    if (sw == 0 && fq == 0) {
        #pragma unroll
        for (int nn = 0; nn < 2; ++nn)
            out[(size_t)B_ * S_ * H_ + b * H_ + hs * HS + gw * 32 + nn * 16 + fr] = cc[nn];
    }
}

extern "C" void kernel_launch(void* const* d_in, const int* in_sizes, int n_in,
                              void* d_out, int out_size, void* d_ws, size_t ws_size,
                              hipStream_t stream) {
    const float* x = (const float*)d_in[0];
    const float* h = (const float*)d_in[1];
    const float* W = (const float*)d_in[2];
    const float* b = (const float*)d_in[3];
    float* out = (float*)d_out;

    _Float16* xh = (_Float16*)d_ws;
    _Float16* Wh = xh + (size_t)B_ * S_ * K_;   // contiguous: Wh - xh = 32MB

    (void)hipFuncSetAttribute((const void*)qrnn_fused,
                              hipFuncAttributeMaxDynamicSharedMemorySize, LDS_BYTES);

    const int n8x = B_ * S_ * K_ / 8;   // 1048576
    const int n8w = 3 * H_ * K_ / 8;    // 196608
    cvt_xw<<<(n8x + n8w + 255) / 256, 256, 0, stream>>>(x, xh, n8x, W, Wh, n8w);

    qrnn_fused<<<B_ * (H_ / HS), 256, LDS_BYTES, stream>>>(xh, Wh, b, h, out);
}